// Round 8
// baseline (224.431 us; speedup 1.0000x reference)
//
#include <hip/hip_runtime.h>

typedef unsigned short u16;
typedef unsigned int u32;
typedef __attribute__((ext_vector_type(8))) short bf16x8;
typedef __attribute__((ext_vector_type(4))) float f32x4;

__device__ __forceinline__ u16 f2bf(float f) {
    u32 u = __float_as_uint(f);
    u += 0x7fffu + ((u >> 16) & 1u);
    return (u16)(u >> 16);
}

// pack two f32 -> one u32 of two bf16 (RNE), 1 VALU inst (vs 3 for shift/and/or)
__device__ __forceinline__ u32 cvtpk(float lo, float hi) {
    u32 r;
    asm("v_cvt_pk_bf16_f32 %0, %1, %2" : "=v"(r) : "v"(lo), "v"(hi));
    return r;
}

// async global->LDS DMA, 16B per lane, LDS dest = wave-uniform base + lane*16
#define GL2LDS(gp, lp)                                                                 \
    __builtin_amdgcn_global_load_lds((const __attribute__((address_space(1))) u32*)(const void*)(gp), \
                                     (__attribute__((address_space(3))) u32*)(void*)(lp), 16, 0, 0)

// ------------- fused prep: cast x (bid<4096) | transpose W (bid<8192) | rtab -------------
__global__ __launch_bounds__(256) void prep_kernel(const float* __restrict__ x,
                                                   const float* __restrict__ Wq,
                                                   const float* __restrict__ Wk,
                                                   const float* __restrict__ Wv,
                                                   const float* __restrict__ Wo,
                                                   const float* __restrict__ wp,
                                                   const float* __restrict__ vp,
                                                   u16* __restrict__ xb,
                                                   u16* __restrict__ Wcat,
                                                   u16* __restrict__ Wot,
                                                   float* __restrict__ tab,
                                                   u32* __restrict__ counter) {
    __shared__ float tl[32][33];
    const int bid = blockIdx.x, t = threadIdx.x;
    if (bid < 4096) {  // ---- cast x fp32 -> bf16, float4/thread ----
        const int i = bid * 256 + t;
        float4 val = ((const float4*)x)[i];
        uint2 o;
        o.x = cvtpk(val.x, val.y);
        o.y = cvtpk(val.z, val.w);
        ((uint2*)xb)[i] = o;
    } else if (bid < 8192) {  // ---- transpose+cast one 32x32 tile of Wq/Wk/Wv/Wo ----
        const int tid = bid - 4096;
        const int zi = tid >> 10, rem = tid & 1023;
        const int kt = (rem >> 5) * 32, nt = (rem & 31) * 32;
        const float* src = (zi == 0) ? Wq : (zi == 1) ? Wk : (zi == 2) ? Wv : Wo;
        u16* dst = (zi < 3) ? (Wcat + zi * 1048576) : Wot;
        const int tx = t & 31, ty = t >> 5;
#pragma unroll
        for (int j = 0; j < 4; ++j)
            tl[ty + j * 8][tx] = src[(kt + ty + j * 8) * 1024 + nt + tx];
        __syncthreads();
#pragma unroll
        for (int j = 0; j < 4; ++j)
            dst[(nt + ty + j * 8) * 1024 + kt + tx] = f2bf(tl[tx][ty + j * 8]);
    } else {  // ---- R_hat table: (1+e^v)/(1+e^(v-w*d))/8 * log2e (exp2-baked) ----
        const int i = (bid - 8192) * 256 + t;  // 16*2048
        if (i == 0) counter[0] = 0u;           // work-stealing counter for attn
        const int h = i >> 11, d = i & 2047;
        const float vv = vp[h], ww = wp[h];
        tab[i] = (1.f + expf(vv)) / (1.f + expf(vv - ww * (float)d)) *
                 (0.125f * 1.44269504088896340736f);
    }
}

// ---------------- m97-style bf16 MFMA GEMM: 128xBN tile, BK=64, global_load_lds ------
// C = A[M][K] @ Bt[N][K]^T.  LDS tiles unpadded, XOR-swizzled (chunk ^= row&7).
// MODE 0: fp32 out + bias.
// MODE 1: col<2048 -> Cb bf16 [M][2048] (Q|K); col>=2048 -> Vt bf16 [1024][4096] (V^T,
//         with seq order inside each 64-block PERMUTED so attn PV A-frags are one 16B:
//         seq = 32a+16b+4c+d  ->  pos = (4a+c)*8 + 4b + d).  [verified R2: conflicts 0]
template <int MODE, int BN>
__global__ __launch_bounds__(256, 3) void gemm128(const u16* __restrict__ A,
                                                  const u16* __restrict__ Bt,
                                                  float* __restrict__ C,
                                                  const float* __restrict__ bias,
                                                  u16* __restrict__ Cb,
                                                  u16* __restrict__ Vt,
                                                  int M, int N, int K) {
    constexpr int NBW = BN / 32;  // 16-wide n-blocks per wave
    __shared__ __align__(16) u16 As[8192];      // 128 rows x 64
    __shared__ __align__(16) u16 Bs[BN * 64];   // BN rows x 64
    const int t = threadIdx.x, lane = t & 63, wv = t >> 6;
    const int l15 = lane & 15, quad = lane >> 4;
    const int m0 = blockIdx.y << 7, n0 = blockIdx.x * BN;
    const int wm = (wv & 1) << 6, wn = (wv >> 1) * (BN / 2);

    f32x4 acc[4][NBW];
#pragma unroll
    for (int i = 0; i < 4; ++i)
#pragma unroll
        for (int j = 0; j < NBW; ++j) acc[i][j] = (f32x4){0.f, 0.f, 0.f, 0.f};

    const int lrow = lane >> 3, lchunk = lane & 7;
    for (int k0 = 0; k0 < K; k0 += 64) {
#pragma unroll
        for (int c = 0; c < 4; ++c) {  // A: 128 rows
            const int r0 = wv * 32 + c * 8;
            const int row = r0 + lrow;
            const int g = lchunk ^ (row & 7);
            GL2LDS(A + (size_t)(m0 + row) * K + k0 + g * 8, &As[r0 * 64]);
        }
#pragma unroll
        for (int c = 0; c < BN / 32; ++c) {  // B: BN rows
            const int r0 = wv * (BN / 4) + c * 8;
            const int row = r0 + lrow;
            const int g = lchunk ^ (row & 7);
            GL2LDS(Bt + (size_t)(n0 + row) * K + k0 + g * 8, &Bs[r0 * 64]);
        }
        __syncthreads();  // drains global_load_lds (vmcnt) + protects prior reads
#pragma unroll
        for (int ks = 0; ks < 2; ++ks) {
            const int p = ((ks << 2) | quad) ^ (l15 & 7);
            bf16x8 af[4], bfr[NBW];
#pragma unroll
            for (int i = 0; i < 4; ++i)
                af[i] = *(const bf16x8*)&As[(wm + i * 16 + l15) * 64 + p * 8];
#pragma unroll
            for (int j = 0; j < NBW; ++j)
                bfr[j] = *(const bf16x8*)&Bs[(wn + j * 16 + l15) * 64 + p * 8];
#pragma unroll
            for (int mb = 0; mb < 4; ++mb)
#pragma unroll
                for (int nb = 0; nb < NBW; ++nb)
                    acc[mb][nb] = __builtin_amdgcn_mfma_f32_16x16x32_bf16(af[mb], bfr[nb],
                                                                          acc[mb][nb], 0, 0, 0);
        }
        __syncthreads();  // protect LDS before next stage overwrites
    }
    // epilogue: C/D layout col=lane&15, row=(lane>>4)*4+reg
    const int rb = m0 + wm + (quad << 2);
    const int cbase = n0 + wn + l15;
#pragma unroll
    for (int mb = 0; mb < 4; ++mb)
#pragma unroll
        for (int nb = 0; nb < NBW; ++nb) {
            const int col = cbase + nb * 16;
            if (MODE == 0) {
#pragma unroll
                for (int r = 0; r < 4; ++r) {
                    const int row = rb + mb * 16 + r;
                    C[(size_t)row * N + col] = acc[mb][nb][r] + bias[col];
                }
            } else if (col < 2048) {  // Q|K: row-major bf16 [M][2048]
#pragma unroll
                for (int r = 0; r < 4; ++r) {
                    const int row = rb + mb * 16 + r;
                    Cb[(size_t)row * 2048 + col] = f2bf(acc[mb][nb][r]);
                }
            } else {  // V: permuted V^T store; lane's 4 seq rows are 4 consecutive pos
                      // seq6 = quad*4 + mb*16 + r -> a=mb>>1, b=mb&1, c=quad, d=r
                const int pos = (((mb >> 1) * 4 + quad) << 3) + ((mb & 1) << 2);
                uint2 o;
                o.x = cvtpk(acc[mb][nb][0], acc[mb][nb][1]);
                o.y = cvtpk(acc[mb][nb][2], acc[mb][nb][3]);
                *(uint2*)(Vt + (size_t)(col - 2048) * 4096 + (m0 + wm) + pos) = o;
            }
        }
}

// ---------------- MFMA flash attention v12: V direct from L2, K-only LDS staging ------
// R5/R7 structure (4-wave blocks, 3/CU, 768 grid, 1-barrier/iter) but V is no longer
// staged in LDS: the XOR-swizzle algebra cancels for the PV A-frag — LDS chunk
// (4ks+quad)^(l15&7) of row db*16+l15 == GLOBAL chunk 4ks+quad of the permuted vtb —
// so each fragment is one clean 16B global load (L2-hot: each V tile re-read by ~32
// time-clustered jobs). The 8 loads issue right after the barrier (OLDEST in vmcnt
// queue: the pre-PV wait leaves the newer K-prefetch in flight — R2 mechanism inverted
// to our favor) and are consumed after exp (~370cyc cover vs ~220 L2 latency).
// Wins: barrier drains 2 GL2LDS/wave (was 4); 8 ds_read_b128/wave-iter removed;
// LDS 41.5->24.6 KB. Cost: +32 VGPR (8 in-flight frags) — (256,3) budget holds (R4).
// qkb: bf16 [4096][2048] (Q|K).  vtb: bf16 [1024][4096] permuted.  rtab fp32 [16][2048].
__global__ __launch_bounds__(256, 3) void attn_kernel(const u16* __restrict__ qkb,
                                                      const u16* __restrict__ vtb,
                                                      const float* __restrict__ rtab,
                                                      u16* __restrict__ ctxb,
                                                      u32* __restrict__ counter) {
    __shared__ __align__(16) u16 Kt[2][4096];   // [kseq][d] swizzled, 8KB x2
    __shared__ __align__(16) float rall[2048];  // R_hat*log2e/8 row for this head
    __shared__ int jobS;

    const int t = threadIdx.x, lane = t & 63, wv = t >> 6;
    const int l15 = lane & 15, quad = lane >> 4;
    const int lrow = lane >> 3, lchunk = lane & 7;

    for (;;) {
        if (t == 0) jobS = (int)atomicAdd(counter, 1u);
        __syncthreads();       // jobS visible; fences prior job's LDS reads
        const int job = jobS;
        if (job >= 1024) break;
        const int qt = 31 - (job >> 5);       // longest jobs first
        const int bh = job & 31;
        const int b = bh >> 4, h = bh & 15;
        const int q0 = qt << 6;

        // rall fill, vectorized f32x4 (q0+64 is a multiple of 64 -> exact)
        {
            const float4* src = (const float4*)(rtab + (h << 11));
            const int nf = (q0 + 64) >> 2;
            for (int i = t; i < nf; i += 256) ((float4*)rall)[i] = src[i];
        }

        // Q as B-operand fragments for S^T: lane n=l15 -> q = q0+wv*16+l15, k=d
        bf16x8 qb[2];
        {
            const u16* qrow = qkb + (size_t)(b * 2048 + q0 + (wv << 4) + l15) * 2048 +
                              (h << 6) + quad * 8;
            qb[0] = *(const bf16x8*)(qrow);
            qb[1] = *(const bf16x8*)(qrow + 32);
        }

        // per-db V base pointers (permuted vtb); per-iter offset = kt*64 + ks*32 (u16)
        const u16* vpd[4];
#pragma unroll
        for (int db = 0; db < 4; ++db)
            vpd[db] = vtb + (size_t)((h << 6) + db * 16 + l15) * 4096 + b * 2048 +
                      (quad << 3);

        f32x4 cacc[4];   // ctx^T accum: db d-blocks, lane holds (d=quad*4+r, q=l15)
#pragma unroll
        for (int i = 0; i < 4; ++i) cacc[i] = (f32x4){0.f, 0.f, 0.f, 0.f};
        f32x4 lacc4 = (f32x4){0.f, 0.f, 0.f, 0.f};  // 4-chain softmax denom partials

        // stage K tile kt=0 into buffer 0 (all 4 waves, 16 rows each)
#pragma unroll
        for (int c = 0; c < 2; ++c) {
            const int r0 = (wv << 4) + c * 8;
            const int row = r0 + lrow;
            const int g = lchunk ^ (row & 7);
            GL2LDS(qkb + (size_t)(b * 2048 + row) * 2048 + 1024 + (h << 6) + g * 8,
                   &Kt[0][r0 * 64]);
        }

        for (int kt = 0; kt <= qt; ++kt) {
            const int bsel = kt & 1;
            __syncthreads();  // drains K staging of buf[bsel] + orders LDS reuse

            // ---- V fragments direct from L2 (issued FIRST: oldest in vmcnt queue,
            //      so the pre-PV wait leaves the newer K-prefetch in flight) ----
            int4 vfr[8];
#pragma unroll
            for (int ks = 0; ks < 2; ++ks)
#pragma unroll
                for (int db = 0; db < 4; ++db)
                    vfr[ks * 4 + db] =
                        *(const int4*)(vpd[db] + (kt << 6) + (ks << 5));

            if (kt < qt) {    // prefetch K tile kt+1 into other buffer
                const int kg0 = (kt + 1) << 6;
#pragma unroll
                for (int c = 0; c < 2; ++c) {
                    const int r0 = (wv << 4) + c * 8;
                    const int row = r0 + lrow;
                    const int g = lchunk ^ (row & 7);
                    GL2LDS(qkb + (size_t)(b * 2048 + kg0 + row) * 2048 + 1024 + (h << 6) + g * 8,
                           &Kt[bsel ^ 1][r0 * 64]);
                }
            }

            // ---- S^T = K @ Q^T : 64 kseq x 16 q per wave (8 MFMA), A=K from LDS ----
            f32x4 sacc[4];
#pragma unroll
            for (int i = 0; i < 4; ++i) sacc[i] = (f32x4){0.f, 0.f, 0.f, 0.f};
            __builtin_amdgcn_s_setprio(1);
#pragma unroll
            for (int ks = 0; ks < 2; ++ks) {
                const int p = ((ks << 2) | quad) ^ (l15 & 7);
#pragma unroll
                for (int mb = 0; mb < 4; ++mb) {
                    bf16x8 ka = *(const bf16x8*)&Kt[bsel][(mb * 16 + l15) * 64 + p * 8];
                    sacc[mb] = __builtin_amdgcn_mfma_f32_16x16x32_bf16(ka, qb[ks],
                                                                       sacc[mb], 0, 0, 0);
                }
            }
            __builtin_amdgcn_s_setprio(0);

            // ---- gate + exp2 (fixed m=0), 4-chain l accum, cvt_pk P to bf16 regs ----
            // lane value (mb,r): q = q0+wv*16+l15, kseq = kg0+mb*16+quad*4+r
            const int D0 = q0 - (kt << 6) + (wv << 4) + l15;  // q - kg0 - local kseq base
            u32 pk[4][2];
            if (kt < qt) {  // off-diagonal: dist >= 1 guaranteed
#pragma unroll
                for (int mb = 0; mb < 4; ++mb) {
                    float pe[4];
#pragma unroll
                    for (int r = 0; r < 4; ++r) {
                        const int dist = D0 - (mb * 16 + (quad << 2) + r);
                        pe[r] = exp2f(fmaxf(sacc[mb][r], 0.f) * rall[dist]);
                        lacc4[r] += pe[r];
                    }
                    pk[mb][0] = cvtpk(pe[0], pe[1]);
                    pk[mb][1] = cvtpk(pe[2], pe[3]);
                }
            } else {  // diagonal tile: causal mask (dist<0 -> 0)
#pragma unroll
                for (int mb = 0; mb < 4; ++mb) {
                    float pe[4];
#pragma unroll
                    for (int r = 0; r < 4; ++r) {
                        const int dist = D0 - (mb * 16 + (quad << 2) + r);
                        const int di = dist < 0 ? 0 : dist;
                        float p0 = exp2f(fmaxf(sacc[mb][r], 0.f) * rall[di]);
                        pe[r] = (dist < 0) ? 0.f : p0;
                        lacc4[r] += pe[r];
                    }
                    pk[mb][0] = cvtpk(pe[0], pe[1]);
                    pk[mb][1] = cvtpk(pe[2], pe[3]);
                }
            }

            // ---- ctx^T += V^T @ P^T : 8 MFMA, A-frag = vfr regs, B-frag = pk regs ----
            __builtin_amdgcn_s_setprio(1);
#pragma unroll
            for (int ks = 0; ks < 2; ++ks) {
                int4 pv = {(int)pk[2 * ks][0], (int)pk[2 * ks][1],
                           (int)pk[2 * ks + 1][0], (int)pk[2 * ks + 1][1]};
                bf16x8 pb = *(bf16x8*)&pv;
#pragma unroll
                for (int db = 0; db < 4; ++db) {
                    bf16x8 vf = *(bf16x8*)&vfr[ks * 4 + db];
                    cacc[db] = __builtin_amdgcn_mfma_f32_16x16x32_bf16(vf, pb,
                                                                       cacc[db], 0, 0, 0);
                }
            }
            __builtin_amdgcn_s_setprio(0);
        }

        // ---- epilogue: l = quad-column reduce; normalize; store ctx (8B/store) ----
        float lt = (lacc4[0] + lacc4[1]) + (lacc4[2] + lacc4[3]);
        lt += __shfl_xor(lt, 16, 64);
        lt += __shfl_xor(lt, 32, 64);
        const float inv = 1.f / lt;
        u16* op = ctxb + (size_t)(b * 2048 + q0 + (wv << 4) + l15) * 1024 +
                  (h << 6) + (quad << 2);
#pragma unroll
        for (int db = 0; db < 4; ++db) {
            uint2 o;
            o.x = cvtpk(cacc[db][0] * inv, cacc[db][1] * inv);
            o.y = cvtpk(cacc[db][2] * inv, cacc[db][3] * inv);
            *(uint2*)(op + db * 16) = o;
        }
        // loop-top __syncthreads() fences these LDS reads before next job's writes
    }
}

extern "C" void kernel_launch(void* const* d_in, const int* in_sizes, int n_in,
                              void* d_out, int out_size, void* d_ws, size_t ws_size,
                              hipStream_t stream) {
    const float* x  = (const float*)d_in[0];
    const float* Wq = (const float*)d_in[1];
    const float* Wk = (const float*)d_in[2];
    const float* Wv = (const float*)d_in[3];
    const float* Wo = (const float*)d_in[4];
    const float* bo = (const float*)d_in[5];
    const float* w  = (const float*)d_in[6];
    const float* v  = (const float*)d_in[7];
    float* out = (float*)d_out;

    char* w8 = (char*)d_ws;
    u16*  xb   = (u16*)(w8);                     //  8 MB : x bf16 [4096][1024]
    u16*  Wcat = (u16*)(w8 + (8u << 20));        //  6 MB : (Wq|Wk|Wv)^T bf16 [3072][1024]
    u16*  Wot  = (u16*)(w8 + (14u << 20));       //  2 MB : Wo^T bf16 [1024][1024]
    u16*  qkb  = (u16*)(w8 + (16u << 20));       // 16 MB : Q|K bf16 [4096][2048]
    u16*  vtb  = (u16*)(w8 + (32u << 20));       //  8 MB : V^T bf16 [1024][4096] (permuted)
    u16*  ctxb = (u16*)(w8 + (40u << 20));       //  8 MB : ctx bf16 [4096][1024]
    float* rtab = (float*)(w8 + (48u << 20));    // 128 KB: R_hat*log2e/8 [16][2048]
    u32*  counter = (u32*)(w8 + (48u << 20) + (1u << 17));  // 4 B : job counter

    // fused prep: cast (4096 blk) | weight transpose (4096 blk) | rtab+counter (128 blk)
    prep_kernel<<<8320, 256, 0, stream>>>(x, Wq, Wk, Wv, Wo, w, v, xb, Wcat, Wot, rtab,
                                          counter);
    // QKV fused projection -> bf16 qkb (Q|K) + V^T direct (permuted)  [M=4096, N=3072, K=1024]
    gemm128<1, 128><<<dim3(24, 32), 256, 0, stream>>>(xb, Wcat, nullptr, nullptr, qkb, vtb,
                                                      4096, 3072, 1024);
    // MFMA flash attention: 768 persistent blocks (3/CU), work-stealing
    attn_kernel<<<768, 256, 0, stream>>>(qkb, vtb, rtab, ctxb, counter);
    // output projection + bias (fp32 out)   [M=4096, N=1024, K=1024], 128x64 tiles
    gemm128<0, 64><<<dim3(16, 32), 256, 0, stream>>>(ctxb, Wot, out, bo, nullptr, nullptr,
                                                     4096, 1024, 1024);
}

// Round 10
// 184.262 us; speedup vs baseline: 1.2180x; 1.2180x over previous
//
#include <hip/hip_runtime.h>

typedef unsigned short u16;
typedef unsigned int u32;
typedef __attribute__((ext_vector_type(8))) short bf16x8;
typedef __attribute__((ext_vector_type(4))) float f32x4;

__device__ __forceinline__ u16 f2bf(float f) {
    u32 u = __float_as_uint(f);
    u += 0x7fffu + ((u >> 16) & 1u);
    return (u16)(u >> 16);
}

// pack two f32 -> one u32 of two bf16 (RNE), 1 VALU inst
__device__ __forceinline__ u32 cvtpk(float lo, float hi) {
    u32 r;
    asm("v_cvt_pk_bf16_f32 %0, %1, %2" : "=v"(r) : "v"(lo), "v"(hi));
    return r;
}

// async global->LDS DMA, 16B per lane, LDS dest = wave-uniform base + lane*16
#define GL2LDS(gp, lp)                                                                 \
    __builtin_amdgcn_global_load_lds((const __attribute__((address_space(1))) u32*)(const void*)(gp), \
                                     (__attribute__((address_space(3))) u32*)(void*)(lp), 16, 0, 0)

#define SBAR                                                                           \
    do {                                                                               \
        __builtin_amdgcn_sched_barrier(0);                                             \
        __builtin_amdgcn_s_barrier();                                                  \
        __builtin_amdgcn_sched_barrier(0);                                             \
    } while (0)
#define WAITV(N)                                                                       \
    do {                                                                               \
        asm volatile("s_waitcnt vmcnt(" #N ")" ::: "memory");                          \
        __builtin_amdgcn_sched_barrier(0);                                             \
    } while (0)

// ------------- fused prep: cast x (bid<4096) | transpose W (bid<8192) | rtab -------------
__global__ __launch_bounds__(256) void prep_kernel(const float* __restrict__ x,
                                                   const float* __restrict__ Wq,
                                                   const float* __restrict__ Wk,
                                                   const float* __restrict__ Wv,
                                                   const float* __restrict__ Wo,
                                                   const float* __restrict__ wp,
                                                   const float* __restrict__ vp,
                                                   u16* __restrict__ xb,
                                                   u16* __restrict__ Wcat,
                                                   u16* __restrict__ Wot,
                                                   float* __restrict__ tab,
                                                   u32* __restrict__ counter) {
    __shared__ float tl[32][33];
    const int bid = blockIdx.x, t = threadIdx.x;
    if (bid < 4096) {  // ---- cast x fp32 -> bf16, float4/thread ----
        const int i = bid * 256 + t;
        float4 val = ((const float4*)x)[i];
        uint2 o;
        o.x = cvtpk(val.x, val.y);
        o.y = cvtpk(val.z, val.w);
        ((uint2*)xb)[i] = o;
    } else if (bid < 8192) {  // ---- transpose+cast one 32x32 tile of Wq/Wk/Wv/Wo ----
        const int tid = bid - 4096;
        const int zi = tid >> 10, rem = tid & 1023;
        const int kt = (rem >> 5) * 32, nt = (rem & 31) * 32;
        const float* src = (zi == 0) ? Wq : (zi == 1) ? Wk : (zi == 2) ? Wv : Wo;
        u16* dst = (zi < 3) ? (Wcat + zi * 1048576) : Wot;
        const int tx = t & 31, ty = t >> 5;
#pragma unroll
        for (int j = 0; j < 4; ++j)
            tl[ty + j * 8][tx] = src[(kt + ty + j * 8) * 1024 + nt + tx];
        __syncthreads();
#pragma unroll
        for (int j = 0; j < 4; ++j)
            dst[(nt + ty + j * 8) * 1024 + kt + tx] = f2bf(tl[tx][ty + j * 8]);
    } else {  // ---- R_hat table: (1+e^v)/(1+e^(v-w*d))/8 * log2e (exp2-baked) ----
        const int i = (bid - 8192) * 256 + t;  // 16*2048
        if (i == 0) counter[0] = 0u;           // work-stealing counter for attn
        const int h = i >> 11, d = i & 2047;
        const float vv = vp[h], ww = wp[h];
        tab[i] = (1.f + expf(vv)) / (1.f + expf(vv - ww * (float)d)) *
                 (0.125f * 1.44269504088896340736f);
    }
}

// ---------------- m97-style bf16 MFMA GEMM: 128xBN tile, BK=64, global_load_lds ------
// C = A[M][K] @ Bt[N][K]^T.  LDS tiles unpadded, XOR-swizzled (chunk ^= row&7).
// MODE 0: fp32 out + bias.
// MODE 1: col<2048 -> Cb bf16 [M][2048] (Q|K); col>=2048 -> Vt bf16 [1024][4096] (V^T,
//         with seq order inside each 64-block PERMUTED so attn PV A-frags are one 16B:
//         seq = 32a+16b+4c+d  ->  pos = (4a+c)*8 + 4b + d).  [verified R2: conflicts 0]
template <int MODE, int BN>
__global__ __launch_bounds__(256, 3) void gemm128(const u16* __restrict__ A,
                                                  const u16* __restrict__ Bt,
                                                  float* __restrict__ C,
                                                  const float* __restrict__ bias,
                                                  u16* __restrict__ Cb,
                                                  u16* __restrict__ Vt,
                                                  int M, int N, int K) {
    constexpr int NBW = BN / 32;  // 16-wide n-blocks per wave
    __shared__ __align__(16) u16 As[8192];      // 128 rows x 64
    __shared__ __align__(16) u16 Bs[BN * 64];   // BN rows x 64
    const int t = threadIdx.x, lane = t & 63, wv = t >> 6;
    const int l15 = lane & 15, quad = lane >> 4;
    const int m0 = blockIdx.y << 7, n0 = blockIdx.x * BN;
    const int wm = (wv & 1) << 6, wn = (wv >> 1) * (BN / 2);

    f32x4 acc[4][NBW];
#pragma unroll
    for (int i = 0; i < 4; ++i)
#pragma unroll
        for (int j = 0; j < NBW; ++j) acc[i][j] = (f32x4){0.f, 0.f, 0.f, 0.f};

    const int lrow = lane >> 3, lchunk = lane & 7;
    for (int k0 = 0; k0 < K; k0 += 64) {
#pragma unroll
        for (int c = 0; c < 4; ++c) {  // A: 128 rows
            const int r0 = wv * 32 + c * 8;
            const int row = r0 + lrow;
            const int g = lchunk ^ (row & 7);
            GL2LDS(A + (size_t)(m0 + row) * K + k0 + g * 8, &As[r0 * 64]);
        }
#pragma unroll
        for (int c = 0; c < BN / 32; ++c) {  // B: BN rows
            const int r0 = wv * (BN / 4) + c * 8;
            const int row = r0 + lrow;
            const int g = lchunk ^ (row & 7);
            GL2LDS(Bt + (size_t)(n0 + row) * K + k0 + g * 8, &Bs[r0 * 64]);
        }
        __syncthreads();  // drains global_load_lds (vmcnt) + protects prior reads
#pragma unroll
        for (int ks = 0; ks < 2; ++ks) {
            const int p = ((ks << 2) | quad) ^ (l15 & 7);
            bf16x8 af[4], bfr[NBW];
#pragma unroll
            for (int i = 0; i < 4; ++i)
                af[i] = *(const bf16x8*)&As[(wm + i * 16 + l15) * 64 + p * 8];
#pragma unroll
            for (int j = 0; j < NBW; ++j)
                bfr[j] = *(const bf16x8*)&Bs[(wn + j * 16 + l15) * 64 + p * 8];
#pragma unroll
            for (int mb = 0; mb < 4; ++mb)
#pragma unroll
                for (int nb = 0; nb < NBW; ++nb)
                    acc[mb][nb] = __builtin_amdgcn_mfma_f32_16x16x32_bf16(af[mb], bfr[nb],
                                                                          acc[mb][nb], 0, 0, 0);
        }
        __syncthreads();  // protect LDS before next stage overwrites
    }
    // epilogue: C/D layout col=lane&15, row=(lane>>4)*4+reg
    const int rb = m0 + wm + (quad << 2);
    const int cbase = n0 + wn + l15;
#pragma unroll
    for (int mb = 0; mb < 4; ++mb)
#pragma unroll
        for (int nb = 0; nb < NBW; ++nb) {
            const int col = cbase + nb * 16;
            if (MODE == 0) {
#pragma unroll
                for (int r = 0; r < 4; ++r) {
                    const int row = rb + mb * 16 + r;
                    C[(size_t)row * N + col] = acc[mb][nb][r] + bias[col];
                }
            } else if (col < 2048) {  // Q|K: row-major bf16 [M][2048]
#pragma unroll
                for (int r = 0; r < 4; ++r) {
                    const int row = rb + mb * 16 + r;
                    Cb[(size_t)row * 2048 + col] = f2bf(acc[mb][nb][r]);
                }
            } else {  // V: permuted V^T store; lane's 4 seq rows are 4 consecutive pos
                const int pos = (((mb >> 1) * 4 + quad) << 3) + ((mb & 1) << 2);
                uint2 o;
                o.x = cvtpk(acc[mb][nb][0], acc[mb][nb][1]);
                o.y = cvtpk(acc[mb][nb][2], acc[mb][nb][3]);
                *(uint2*)(Vt + (size_t)(col - 2048) * 4096 + (m0 + wm) + pos) = o;
            }
        }
}

// ---------------- MFMA flash attention v13: counted-vmcnt deep pipeline ----------------
// R7 per-wave compute, new sync structure (T4): raw s_barrier + counted vmcnt instead
// of __syncthreads full-drain.  K: 3 buffers, depth-2 prefetch (issue kt+2 post-b1) ->
// ~2 iters cover.  V: 2 buffers, depth-1 (issue kt+1 post-b1), landed at a SECOND
// barrier placed just before PV -> ~1.4 iters cover.  Role-split waits: K-waves
// vmcnt(4) pre-b1 (retire K kt, leave K kt+1 flying); V-waves vmcnt(4) pre-b2 (retire
// V kt, leave V kt+1).  In-order vmem retirement makes the counts exact even with the
// rall/qb loads ahead in the queue (they retire first, conservatively); tail iters
// use vmcnt(0).  Hazards: every buffer written at iter kt was last read at kt-1, and
// issue is post-b1-of-kt which all waves reach only after finishing kt-1 (readers'
// lgkm waits precede their MFMAs which precede the barrier).
// LDS 48.1KB -> still 3 blocks/CU (R6 lesson).  rall stays in LDS (R2 lesson); no
// launch_bounds tightening (R4 lesson).  [R9 infra-failed; resubmitted unchanged]
__global__ __launch_bounds__(256, 3) void attn_kernel(const u16* __restrict__ qkb,
                                                      const u16* __restrict__ vtb,
                                                      const float* __restrict__ rtab,
                                                      u16* __restrict__ ctxb,
                                                      u32* __restrict__ counter) {
    __shared__ __align__(16) u16 Kt[3][4096];   // [kseq][d] swizzled, 8KB x3
    __shared__ __align__(16) u16 Vt2[2][4096];  // [d][kseq-permuted] swizzled, 8KB x2
    __shared__ __align__(16) float rall[2048];  // R_hat*log2e/8 row for this head
    __shared__ int jobS;

    const int t = threadIdx.x, lane = t & 63, wv = t >> 6;
    const int l15 = lane & 15, quad = lane >> 4;
    const int lrow = lane >> 3, lchunk = lane & 7;
    const int half0 = (wv & 1) * 32;

    for (;;) {
        if (t == 0) jobS = (int)atomicAdd(counter, 1u);
        __syncthreads();       // jobS visible; full fence between jobs
        const int job = jobS;
        if (job >= 1024) break;
        const int qt = 31 - (job >> 5);       // longest jobs first
        const int bh = job & 31;
        const int b = bh >> 4, h = bh & 15;
        const int q0 = qt << 6;

        // rall fill, vectorized f32x4 (q0+64 is a multiple of 64 -> exact)
        {
            const float4* src = (const float4*)(rtab + (h << 11));
            const int nf = (q0 + 64) >> 2;
            for (int i = t; i < nf; i += 256) ((float4*)rall)[i] = src[i];
        }

        // Q as B-operand fragments for S^T: lane n=l15 -> q = q0+wv*16+l15, k=d
        bf16x8 qb[2];
        {
            const u16* qrow = qkb + (size_t)(b * 2048 + q0 + (wv << 4) + l15) * 2048 +
                              (h << 6) + quad * 8;
            qb[0] = *(const bf16x8*)(qrow);
            qb[1] = *(const bf16x8*)(qrow + 32);
        }

        // staging lambdas: waves 0,1 own K rows half0..half0+31; waves 2,3 own V rows
        auto stage_k = [&](int ktile, int kb) {
#pragma unroll
            for (int c = 0; c < 4; ++c) {
                const int r0 = half0 + c * 8;
                const int row = r0 + lrow;
                const int g = lchunk ^ (row & 7);
                GL2LDS(qkb + (size_t)(b * 2048 + (ktile << 6) + row) * 2048 + 1024 +
                           (h << 6) + g * 8,
                       &Kt[kb][r0 * 64]);
            }
        };
        auto stage_v = [&](int ktile, int vb) {
#pragma unroll
            for (int c = 0; c < 4; ++c) {
                const int r0 = half0 + c * 8;
                const int row = r0 + lrow;
                const int g = lchunk ^ (row & 7);
                GL2LDS(vtb + (size_t)((h << 6) + row) * 4096 + b * 2048 + (ktile << 6) +
                           g * 8,
                       &Vt2[vb][r0 * 64]);
            }
        };

        f32x4 cacc[4];   // ctx^T accum: db d-blocks, lane holds (d=quad*4+r, q=l15)
#pragma unroll
        for (int i = 0; i < 4; ++i) cacc[i] = (f32x4){0.f, 0.f, 0.f, 0.f};
        f32x4 lacc4 = (f32x4){0.f, 0.f, 0.f, 0.f};  // 4-chain softmax denom partials

        // prologue: K depth-2 (kt=0,1), V depth-1 (kt=0)
        if (wv < 2) {
            stage_k(0, 0);
            if (qt >= 1) stage_k(1, 1);
        } else {
            stage_v(0, 0);
        }
        asm volatile("s_waitcnt lgkmcnt(0)" ::: "memory");  // publish rall fill at b1
        __builtin_amdgcn_sched_barrier(0);

        for (int kt = 0; kt <= qt; ++kt) {
            const int kb = kt % 3, vb = kt & 1;
            // ---- pre-b1: K-waves retire K kt (leave K kt+1 in flight) ----
            if (wv < 2) {
                if (kt < qt) WAITV(4);
                else         WAITV(0);
            }
            SBAR;  // b1: Kt[kb] ready for all waves
            // ---- issue next tiles (targets last read at iter kt-1: safe post-b1) ----
            if (wv < 2) {
                if (kt + 2 <= qt) stage_k(kt + 2, (kt + 2) % 3);
            } else {
                if (kt + 1 <= qt) stage_v(kt + 1, (kt + 1) & 1);
            }

            // ---- S^T = K @ Q^T : 8 MFMA, A=K from LDS ----
            f32x4 sacc[4];
#pragma unroll
            for (int i = 0; i < 4; ++i) sacc[i] = (f32x4){0.f, 0.f, 0.f, 0.f};
            __builtin_amdgcn_s_setprio(1);
#pragma unroll
            for (int ks = 0; ks < 2; ++ks) {
                const int p = ((ks << 2) | quad) ^ (l15 & 7);
#pragma unroll
                for (int mb = 0; mb < 4; ++mb) {
                    bf16x8 ka = *(const bf16x8*)&Kt[kb][(mb * 16 + l15) * 64 + p * 8];
                    sacc[mb] = __builtin_amdgcn_mfma_f32_16x16x32_bf16(ka, qb[ks],
                                                                       sacc[mb], 0, 0, 0);
                }
            }
            __builtin_amdgcn_s_setprio(0);

            // ---- gate + exp2 (fixed m=0), 4-chain l accum, cvt_pk P to bf16 regs ----
            const int D0 = q0 - (kt << 6) + (wv << 4) + l15;
            u32 pk[4][2];
            if (kt < qt) {  // off-diagonal: dist >= 1 guaranteed
#pragma unroll
                for (int mb = 0; mb < 4; ++mb) {
                    float pe[4];
#pragma unroll
                    for (int r = 0; r < 4; ++r) {
                        const int dist = D0 - (mb * 16 + (quad << 2) + r);
                        pe[r] = exp2f(fmaxf(sacc[mb][r], 0.f) * rall[dist]);
                        lacc4[r] += pe[r];
                    }
                    pk[mb][0] = cvtpk(pe[0], pe[1]);
                    pk[mb][1] = cvtpk(pe[2], pe[3]);
                }
            } else {  // diagonal tile: causal mask (dist<0 -> 0)
#pragma unroll
                for (int mb = 0; mb < 4; ++mb) {
                    float pe[4];
#pragma unroll
                    for (int r = 0; r < 4; ++r) {
                        const int dist = D0 - (mb * 16 + (quad << 2) + r);
                        const int di = dist < 0 ? 0 : dist;
                        float p0 = exp2f(fmaxf(sacc[mb][r], 0.f) * rall[di]);
                        pe[r] = (dist < 0) ? 0.f : p0;
                        lacc4[r] += pe[r];
                    }
                    pk[mb][0] = cvtpk(pe[0], pe[1]);
                    pk[mb][1] = cvtpk(pe[2], pe[3]);
                }
            }

            // ---- pre-b2: V-waves retire V kt (leave V kt+1 in flight) ----
            if (wv >= 2) {
                if (kt < qt) WAITV(4);
                else         WAITV(0);
            }
            SBAR;  // b2: Vt2[vb] ready for all waves

            // ---- ctx^T += V^T @ P^T : 8 MFMA, A-frag one b128 (permuted Vt2) ----
            __builtin_amdgcn_s_setprio(1);
#pragma unroll
            for (int ks = 0; ks < 2; ++ks) {
                int4 pv = {(int)pk[2 * ks][0], (int)pk[2 * ks][1],
                           (int)pk[2 * ks + 1][0], (int)pk[2 * ks + 1][1]};
                bf16x8 pb = *(bf16x8*)&pv;
                const int g = (4 * ks + quad) ^ (l15 & 7);
#pragma unroll
                for (int db = 0; db < 4; ++db) {
                    bf16x8 vf = *(const bf16x8*)&Vt2[vb][(db * 16 + l15) * 64 + g * 8];
                    cacc[db] = __builtin_amdgcn_mfma_f32_16x16x32_bf16(vf, pb,
                                                                       cacc[db], 0, 0, 0);
                }
            }
            __builtin_amdgcn_s_setprio(0);
        }

        // ---- epilogue: l = quad-column reduce; normalize; store ctx (8B/store) ----
        float lt = (lacc4[0] + lacc4[1]) + (lacc4[2] + lacc4[3]);
        lt += __shfl_xor(lt, 16, 64);
        lt += __shfl_xor(lt, 32, 64);
        const float inv = 1.f / lt;
        u16* op = ctxb + (size_t)(b * 2048 + q0 + (wv << 4) + l15) * 1024 +
                  (h << 6) + (quad << 2);
#pragma unroll
        for (int db = 0; db < 4; ++db) {
            uint2 o;
            o.x = cvtpk(cacc[db][0] * inv, cacc[db][1] * inv);
            o.y = cvtpk(cacc[db][2] * inv, cacc[db][3] * inv);
            *(uint2*)(op + db * 16) = o;
        }
        // job-top __syncthreads fences these LDS reads before next job's writes
    }
}

extern "C" void kernel_launch(void* const* d_in, const int* in_sizes, int n_in,
                              void* d_out, int out_size, void* d_ws, size_t ws_size,
                              hipStream_t stream) {
    const float* x  = (const float*)d_in[0];
    const float* Wq = (const float*)d_in[1];
    const float* Wk = (const float*)d_in[2];
    const float* Wv = (const float*)d_in[3];
    const float* Wo = (const float*)d_in[4];
    const float* bo = (const float*)d_in[5];
    const float* w  = (const float*)d_in[6];
    const float* v  = (const float*)d_in[7];
    float* out = (float*)d_out;

    char* w8 = (char*)d_ws;
    u16*  xb   = (u16*)(w8);                     //  8 MB : x bf16 [4096][1024]
    u16*  Wcat = (u16*)(w8 + (8u << 20));        //  6 MB : (Wq|Wk|Wv)^T bf16 [3072][1024]
    u16*  Wot  = (u16*)(w8 + (14u << 20));       //  2 MB : Wo^T bf16 [1024][1024]
    u16*  qkb  = (u16*)(w8 + (16u << 20));       // 16 MB : Q|K bf16 [4096][2048]
    u16*  vtb  = (u16*)(w8 + (32u << 20));       //  8 MB : V^T bf16 [1024][4096] (permuted)
    u16*  ctxb = (u16*)(w8 + (40u << 20));       //  8 MB : ctx bf16 [4096][1024]
    float* rtab = (float*)(w8 + (48u << 20));    // 128 KB: R_hat*log2e/8 [16][2048]
    u32*  counter = (u32*)(w8 + (48u << 20) + (1u << 17));  // 4 B : job counter

    // fused prep: cast (4096 blk) | weight transpose (4096 blk) | rtab+counter (128 blk)
    prep_kernel<<<8320, 256, 0, stream>>>(x, Wq, Wk, Wv, Wo, w, v, xb, Wcat, Wot, rtab,
                                          counter);
    // QKV fused projection -> bf16 qkb (Q|K) + V^T direct (permuted)  [M=4096, N=3072, K=1024]
    gemm128<1, 128><<<dim3(24, 32), 256, 0, stream>>>(xb, Wcat, nullptr, nullptr, qkb, vtb,
                                                      4096, 3072, 1024);
    // MFMA flash attention: 768 persistent blocks (3/CU), work-stealing
    attn_kernel<<<768, 256, 0, stream>>>(qkb, vtb, rtab, ctxb, counter);
    // output projection + bias (fp32 out)   [M=4096, N=1024, K=1024], 128x64 tiles
    gemm128<0, 64><<<dim3(16, 32), 256, 0, stream>>>(ctxb, Wot, out, bo, nullptr, nullptr,
                                                     4096, 1024, 1024);
}